// Round 1
// baseline (665.131 us; speedup 1.0000x reference)
//
#include <hip/hip_runtime.h>
#include <stdint.h>

// ---------------- types ----------------
typedef short bf16x8 __attribute__((ext_vector_type(8)));          // 8 bf16 in 4 VGPRs (MFMA A/B frag)
typedef float f32x4 __attribute__((ext_vector_type(4)));           // MFMA C/D frag
typedef unsigned short u16x8 __attribute__((ext_vector_type(8)));  // 16B bf16 chunk

#define N_NODES 50000
#define DIM 512                  // feature width
#define KDIM 1024                // GEMM K = [h | agg]
#define NPAD 50048               // 391 * 128
#define M_TILES 391
#define GEMM_GRID 1568           // 8 XCDs * 196 slots (4 guard blocks idle)
#define FLAT_TOTAL 25600000ULL   // N_NODES * DIM
#define NBLK_AGG 12500           // N_NODES / 4 rows per block

__device__ __forceinline__ unsigned short f2bf(float f) {
    unsigned u = __float_as_uint(f);
    unsigned r = u + 0x7FFFu + ((u >> 16) & 1u);   // RNE
    return (unsigned short)(r >> 16);
}
__device__ __forceinline__ float bf2f(unsigned short h) {
    return __uint_as_float(((unsigned)h) << 16);
}

// async global -> LDS, 16B per lane. LDS dest must be wave-uniform base + lane*16.
__device__ __forceinline__ void llds16(const void* g, void* l) {
    __builtin_amdgcn_global_load_lds(
        (const __attribute__((address_space(1))) void*)g,
        (__attribute__((address_space(3))) void*)l,
        16, 0, 0);
}

// ---------------- cast x: fp32 [50000,512] -> bf16 into XA[:, 0:512] (stride 1024) ----------------
__global__ void cast_x(const float* __restrict__ x, unsigned short* __restrict__ XA) {
    size_t idx = ((size_t)blockIdx.x * blockDim.x + threadIdx.x) * 8;  // 12500*256*8 = 25.6M exactly
    float4 v0 = *(const float4*)&x[idx];
    float4 v1 = *(const float4*)&x[idx + 4];
    u16x8 r;
    r[0] = f2bf(v0.x); r[1] = f2bf(v0.y); r[2] = f2bf(v0.z); r[3] = f2bf(v0.w);
    r[4] = f2bf(v1.x); r[5] = f2bf(v1.y); r[6] = f2bf(v1.z); r[7] = f2bf(v1.w);
    size_t row = idx >> 9;
    size_t col = idx & 511;
    *(u16x8*)&XA[row * KDIM + col] = r;
}

// ---------------- both W [512,1024] fp32 -> bf16, straight layout, one launch ----------------
__global__ void cast_w2(const float* __restrict__ w1, const float* __restrict__ w2,
                        unsigned short* __restrict__ o1, unsigned short* __restrict__ o2) {
    int b = blockIdx.x;
    const float* w = (b < 256) ? w1 : w2;
    unsigned short* o = (b < 256) ? o1 : o2;
    int idx = ((b & 255) * 256 + threadIdx.x) * 8;     // 524288 elems per matrix
    float4 v0 = *(const float4*)&w[idx];
    float4 v1 = *(const float4*)&w[idx + 4];
    u16x8 r;
    r[0] = f2bf(v0.x); r[1] = f2bf(v0.y); r[2] = f2bf(v0.z); r[3] = f2bf(v0.w);
    r[4] = f2bf(v1.x); r[5] = f2bf(v1.y); r[6] = f2bf(v1.z); r[7] = f2bf(v1.w);
    *(u16x8*)&o[idx] = r;
}

// ---------------- agg: buf[i, 512:1024] = 0.5*(buf[n0, 0:512] + buf[n1, 0:512]) ----------------
// Linear-mean moved BEFORE the matmul (mean is linear, so agg@Wn == mean(Q) exactly up to
// one bf16 rounding). Gathered rows are 1 KB contiguous; source (<=51.2 MB) is L3-resident.
// Writes (cols 512..1023) are disjoint from reads (cols 0..511) -> no cross-block hazard.
__global__ void agg_mean(unsigned short* __restrict__ buf, const int* __restrict__ nb) {
    int t = threadIdx.x;
    int i = blockIdx.x * 4 + (t >> 6);          // 4 rows per block, one wave each
    int lane = t & 63;
    int c = lane * 8;
    int n0 = nb[i * 2], n1 = nb[i * 2 + 1];
    u16x8 a = *(const u16x8*)&buf[(size_t)n0 * KDIM + c];
    u16x8 b = *(const u16x8*)&buf[(size_t)n1 * KDIM + c];
    u16x8 o;
#pragma unroll
    for (int j = 0; j < 8; j++)
        o[j] = f2bf(0.5f * (bf2f(a[j]) + bf2f(b[j])));
    *(u16x8*)&buf[(size_t)i * KDIM + 512 + c] = o;
}

// ---------------- GEMM: H[M,512] = relu(A[M,1024] * B[512,1024]^T), K=1024 ----------------
// EPI==1: store bf16 relu into H (stride KDIM, cols 0..511 of the next layer's [h|agg] buffer).
// EPI==2: store fp32 relu into out[row*512+col] (rows<50000) + fused FC dot partials vs fcw.
// XCD-affinity swizzle: block->XCD is round-robin (%8); XCD x owns bm%8==x and the 4
// bn-blocks of one bm are adjacent in dispatch -> A-tile fetched from HBM once, re-read
// 3x from that XCD's own L2.
template <int EPI>
__global__ __launch_bounds__(256)
void gemm_nt(const unsigned short* __restrict__ A, const unsigned short* __restrict__ B,
             unsigned short* __restrict__ H, const float* __restrict__ fcw,
             float* __restrict__ out, float2* __restrict__ partials) {
    __shared__ unsigned short As[2][128 * 32];   // 2 x 8 KB (k-halves)
    __shared__ unsigned short Bs[2][128 * 32];   // 2 x 8 KB
    __shared__ float r0[4], r1[4];

    int x = blockIdx.x & 7;            // XCD id (round-robin heuristic)
    int g = blockIdx.x >> 3;           // 0..195 within XCD
    int bm = x + 8 * (g >> 2);         // bm % 8 == x
    int bn = g & 3;
    if (bm >= M_TILES) {               // 4 guard blocks idle
        if (EPI == 2 && threadIdx.x == 0) partials[blockIdx.x] = make_float2(0.f, 0.f);
        return;
    }

    int t = threadIdx.x;
    int lane = t & 63;
    int wave = t >> 6;
    int m_off = (wave >> 1) * 64;      // 2x2 waves over the 128x128 tile
    int n_off = (wave & 1) * 64;
    int lrow = lane & 15;
    int lk = (lane >> 4) * 8;

    f32x4 acc[4][4];
#pragma unroll
    for (int i = 0; i < 4; i++)
#pragma unroll
        for (int j = 0; j < 4; j++) acc[i][j] = (f32x4){0.f, 0.f, 0.f, 0.f};

    // staging: thread t covers 16B chunk (row t>>2, chunk t&3) and same +64 rows
    const unsigned short* ga = A + (size_t)(bm * 128 + (t >> 2)) * KDIM + (t & 3) * 8;
    const unsigned short* gb = B + (size_t)(bn * 128 + (t >> 2)) * KDIM + (t & 3) * 8;

    for (int k0 = 0; k0 < KDIM; k0 += 64) {    // 16 iterations
        __syncthreads();                       // prev iter's ds_reads done before overwrite
        llds16(ga + k0,             &As[0][t * 8]);
        llds16(ga + k0 + 64 * KDIM, &As[0][t * 8 + 2048]);
        llds16(gb + k0,             &Bs[0][t * 8]);
        llds16(gb + k0 + 64 * KDIM, &Bs[0][t * 8 + 2048]);
        llds16(ga + k0 + 32,             &As[1][t * 8]);
        llds16(ga + k0 + 32 + 64 * KDIM, &As[1][t * 8 + 2048]);
        llds16(gb + k0 + 32,             &Bs[1][t * 8]);
        llds16(gb + k0 + 32 + 64 * KDIM, &Bs[1][t * 8 + 2048]);
        __syncthreads();                       // drains vmcnt -> LDS valid

#pragma unroll
        for (int h = 0; h < 2; h++) {
            bf16x8 af[4], bfr[4];
#pragma unroll
            for (int i = 0; i < 4; i++)
                af[i] = *(const bf16x8*)&As[h][(m_off + i * 16 + lrow) * 32 + lk];
#pragma unroll
            for (int j = 0; j < 4; j++)
                bfr[j] = *(const bf16x8*)&Bs[h][(n_off + j * 16 + lrow) * 32 + lk];
#pragma unroll
            for (int i = 0; i < 4; i++)
#pragma unroll
                for (int j = 0; j < 4; j++)
                    acc[i][j] = __builtin_amdgcn_mfma_f32_16x16x32_bf16(af[i], bfr[j], acc[i][j], 0, 0, 0);
        }
    }

    // epilogue: C/D layout col=lane&15, row=(lane>>4)*4+reg
    int lc = lane & 15;
    int lr = (lane >> 4) << 2;

    if (EPI == 1) {
#pragma unroll
        for (int i = 0; i < 4; i++) {
            int row0 = bm * 128 + m_off + i * 16 + lr;
#pragma unroll
            for (int j = 0; j < 4; j++) {
                int col = bn * 128 + n_off + j * 16 + lc;
                f32x4 v = acc[i][j];
#pragma unroll
                for (int r = 0; r < 4; r++)
                    H[(size_t)(row0 + r) * KDIM + col] = f2bf(fmaxf(v[r], 0.f));
            }
        }
    } else {
        float s0 = 0.f, s1 = 0.f;
#pragma unroll
        for (int i = 0; i < 4; i++) {
            int row0 = bm * 128 + m_off + i * 16 + lr;
#pragma unroll
            for (int j = 0; j < 4; j++) {
                int col = bn * 128 + n_off + j * 16 + lc;
                f32x4 v = acc[i][j];
#pragma unroll
                for (int r = 0; r < 4; r++) {
                    int row = row0 + r;
                    if (row < N_NODES) {               // pad rows excluded from out + FC
                        float vv = fmaxf(v[r], 0.f);
                        size_t off = (size_t)row * DIM + col;
                        out[off] = vv;
                        s0 += vv * fcw[off];
                        s1 += vv * fcw[FLAT_TOTAL + off];
                    }
                }
            }
        }
#pragma unroll
        for (int off = 32; off > 0; off >>= 1) {
            s0 += __shfl_down(s0, off);
            s1 += __shfl_down(s1, off);
        }
        if (lane == 0) { r0[wave] = s0; r1[wave] = s1; }
        __syncthreads();
        if (t == 0)
            partials[blockIdx.x] = make_float2(r0[0] + r0[1] + r0[2] + r0[3],
                                               r1[0] + r1[1] + r1[2] + r1[3]);
    }
}

// ---------------- final reduce + log_softmax ----------------
__global__ void reduce_finalize(const float2* __restrict__ partials, const float* __restrict__ fcb,
                                float* __restrict__ out2) {
    float s0 = 0.f, s1 = 0.f;
    for (int k = threadIdx.x; k < GEMM_GRID; k += 1024) {
        float2 pr = partials[k];
        s0 += pr.x; s1 += pr.y;
    }
#pragma unroll
    for (int off = 32; off > 0; off >>= 1) {
        s0 += __shfl_down(s0, off);
        s1 += __shfl_down(s1, off);
    }
    __shared__ float r0[16], r1[16];
    int lane = threadIdx.x & 63, w = threadIdx.x >> 6;
    if (lane == 0) { r0[w] = s0; r1[w] = s1; }
    __syncthreads();
    if (threadIdx.x == 0) {
        float l0 = fcb[0], l1 = fcb[1];
#pragma unroll
        for (int k = 0; k < 16; k++) { l0 += r0[k]; l1 += r1[k]; }
        float m = fmaxf(l0, l1);
        float lse = m + logf(expf(l0 - m) + expf(l1 - m));
        out2[0] = l0 - lse;
        out2[1] = l1 - lse;
    }
}

// ---------------- launch ----------------
extern "C" void kernel_launch(void* const* d_in, const int* in_sizes, int n_in,
                              void* d_out, int out_size, void* d_ws, size_t ws_size,
                              hipStream_t stream) {
    const float* x   = (const float*)d_in[0];
    const int*   n1  = (const int*)d_in[1];
    const int*   n2  = (const int*)d_in[2];
    const float* W1  = (const float*)d_in[3];
    const float* W2  = (const float*)d_in[4];
    const float* fcw = (const float*)d_in[5];
    const float* fcb = (const float*)d_in[6];
    float* out = (float*)d_out;

    // workspace layout (16B aligned). Pad rows (50000..50047) stay 0xAA poison = tiny
    // finite bf16 values -> safe garbage through the GEMMs, masked out of the output.
    char* ws = (char*)d_ws;
    const size_t XA_OFF = 0;                                     // NPAD*1024 bf16 = 102.5 MB  [x | agg1]
    const size_t HA_OFF = XA_OFF + (size_t)NPAD * KDIM * 2;      // NPAD*1024 bf16 = 102.5 MB  [h1 | agg2]
    const size_t W1_OFF = HA_OFF + (size_t)NPAD * KDIM * 2;      // 1 MB
    const size_t W2_OFF = W1_OFF + (size_t)DIM * KDIM * 2;       // 1 MB
    const size_t P_OFF  = W2_OFF + (size_t)DIM * KDIM * 2;       // GEMM_GRID float2
    unsigned short* XA  = (unsigned short*)(ws + XA_OFF);
    unsigned short* HA  = (unsigned short*)(ws + HA_OFF);
    unsigned short* W1r = (unsigned short*)(ws + W1_OFF);
    unsigned short* W2r = (unsigned short*)(ws + W2_OFF);
    float2* partials    = (float2*)(ws + P_OFF);

    cast_w2<<<512, 256, 0, stream>>>(W1, W2, W1r, W2r);
    cast_x<<<12500, 256, 0, stream>>>(x, XA);

    agg_mean<<<NBLK_AGG, 256, 0, stream>>>(XA, n1);
    gemm_nt<1><<<GEMM_GRID, 256, 0, stream>>>(XA, W1r, HA, nullptr, nullptr, nullptr);
    agg_mean<<<NBLK_AGG, 256, 0, stream>>>(HA, n2);
    gemm_nt<2><<<GEMM_GRID, 256, 0, stream>>>(HA, W2r, nullptr, fcw, out, partials);

    reduce_finalize<<<1, 1024, 0, stream>>>(partials, fcb, out + FLAT_TOTAL);
}

// Round 3
// 627.686 us; speedup vs baseline: 1.0597x; 1.0597x over previous
//
#include <hip/hip_runtime.h>
#include <stdint.h>

// ---------------- types ----------------
typedef short bf16x8 __attribute__((ext_vector_type(8)));          // 8 bf16 in 4 VGPRs (MFMA A/B frag)
typedef float f32x4 __attribute__((ext_vector_type(4)));           // MFMA C/D frag
typedef unsigned short u16x8 __attribute__((ext_vector_type(8)));  // 16B bf16 chunk

#define N_NODES 50000
#define DIM 512                  // feature width
#define KDIM 1024                // GEMM K = [h | agg]
#define NPAD 50048               // 391 * 128
#define M_TILES 391              // 128-row tiles
#define GEMM_GRID 3136           // 8 XCDs * 392 slots (8 guard blocks idle); 391 bm x 8 bn useful
#define FLAT_TOTAL 25600000ULL   // N_NODES * DIM
#define NBLK_AGG 12500           // N_NODES / 4 rows per block

__device__ __forceinline__ unsigned short f2bf(float f) {
    unsigned u = __float_as_uint(f);
    unsigned r = u + 0x7FFFu + ((u >> 16) & 1u);   // RNE
    return (unsigned short)(r >> 16);
}
__device__ __forceinline__ float bf2f(unsigned short h) {
    return __uint_as_float(((unsigned)h) << 16);
}

// async global -> LDS, 16B per lane. LDS dest must be wave-uniform base + lane*16.
__device__ __forceinline__ void llds16(const void* g, void* l) {
    __builtin_amdgcn_global_load_lds(
        (const __attribute__((address_space(1))) void*)g,
        (__attribute__((address_space(3))) void*)l,
        16, 0, 0);
}

// ---------------- cast x: fp32 [50000,512] -> bf16 into XA[:, 0:512] (stride 1024) ----------------
__global__ void cast_x(const float* __restrict__ x, unsigned short* __restrict__ XA) {
    size_t idx = ((size_t)blockIdx.x * blockDim.x + threadIdx.x) * 8;  // 12500*256*8 = 25.6M exactly
    float4 v0 = *(const float4*)&x[idx];
    float4 v1 = *(const float4*)&x[idx + 4];
    u16x8 r;
    r[0] = f2bf(v0.x); r[1] = f2bf(v0.y); r[2] = f2bf(v0.z); r[3] = f2bf(v0.w);
    r[4] = f2bf(v1.x); r[5] = f2bf(v1.y); r[6] = f2bf(v1.z); r[7] = f2bf(v1.w);
    size_t row = idx >> 9;
    size_t col = idx & 511;
    *(u16x8*)&XA[row * KDIM + col] = r;
}

// ---------------- both W [512,1024] fp32 -> bf16, straight layout, one launch ----------------
__global__ void cast_w2(const float* __restrict__ w1, const float* __restrict__ w2,
                        unsigned short* __restrict__ o1, unsigned short* __restrict__ o2) {
    int b = blockIdx.x;
    const float* w = (b < 256) ? w1 : w2;
    unsigned short* o = (b < 256) ? o1 : o2;
    int idx = ((b & 255) * 256 + threadIdx.x) * 8;     // 524288 elems per matrix
    float4 v0 = *(const float4*)&w[idx];
    float4 v1 = *(const float4*)&w[idx + 4];
    u16x8 r;
    r[0] = f2bf(v0.x); r[1] = f2bf(v0.y); r[2] = f2bf(v0.z); r[3] = f2bf(v0.w);
    r[4] = f2bf(v1.x); r[5] = f2bf(v1.y); r[6] = f2bf(v1.z); r[7] = f2bf(v1.w);
    *(u16x8*)&o[idx] = r;
}

// ---------------- agg: buf[i, 512:1024] = 0.5*(buf[n0, 0:512] + buf[n1, 0:512]) ----------------
// Linear-mean moved BEFORE the matmul. Gathered rows are 1 KB contiguous; source L3-resident.
// Writes (cols 512..1023) are disjoint from reads (cols 0..511) -> no cross-block hazard.
__global__ void agg_mean(unsigned short* __restrict__ buf, const int* __restrict__ nb) {
    int t = threadIdx.x;
    int i = blockIdx.x * 4 + (t >> 6);          // 4 rows per block, one wave each
    int lane = t & 63;
    int c = lane * 8;
    int n0 = nb[i * 2], n1 = nb[i * 2 + 1];
    u16x8 a = *(const u16x8*)&buf[(size_t)n0 * KDIM + c];
    u16x8 b = *(const u16x8*)&buf[(size_t)n1 * KDIM + c];
    u16x8 o;
#pragma unroll
    for (int j = 0; j < 8; j++)
        o[j] = f2bf(0.5f * (bf2f(a[j]) + bf2f(b[j])));
    *(u16x8*)&buf[(size_t)i * KDIM + 512 + c] = o;
}

// ---------------- GEMM: H[M,512] = relu(A[M,1024] * B[512,1024]^T) ----------------
// 128x64 tile, K-step 32, 2-phase prefetch pipeline (T3-minimum: stage k+1, compute k,
// full-drain barrier once per k-step -> prefetch latency hides under compute).
// RACE FIX (r2 tripwire): the barrier must drain lgkmcnt TOO. With vmcnt-only, a wave
// signals the barrier while its ds_reads are in flight (MFMAs sunk past the barrier per
// rule #18) and another wave's global_load_lds overwrites the buffer -> corrupted reads.
// sched_barrier(0) on both sides pins code motion around the inline-asm waits.
// LDS 24.6 KB -> 6 blocks/CU. XOR-swizzled LDS (both-sides, rule #21): linear dest for
// global_load_lds, pre-swizzled GLOBAL source chunk, swizzled ds_read offset.
// EPI==1: bf16 relu into H (stride KDIM, cols 0..511 of next layer's [h|agg] buffer).
// EPI==2: fp32 relu into out (rows<50000) + fused FC dot partials vs fcw.

#define SYNC0() do { \
    asm volatile("s_waitcnt vmcnt(0) lgkmcnt(0)" ::: "memory"); \
    __builtin_amdgcn_sched_barrier(0); \
    __builtin_amdgcn_s_barrier(); \
    __builtin_amdgcn_sched_barrier(0); \
} while (0)

// stage k-step ks into buffer s: A tile 128x32 (8 KB, shorts 0..4095), B tile 64x32 (4 KB, 4096..6143)
#define STAGE(s, ks) do { \
    int koff_ = (ks) * 32; \
    llds16(ga + koff_,            &S[s][t * 8]); \
    llds16(ga + koff_ + 64*KDIM,  &S[s][2048 + t * 8]); \
    llds16(gb + koff_,            &S[s][4096 + t * 8]); \
} while (0)

#define COMPUTE(s) do { \
    bf16x8 af[4], bfr[2]; \
    _Pragma("unroll") \
    for (int i_ = 0; i_ < 4; i_++) af[i_] = *(const bf16x8*)&S[s][aoff[i_]]; \
    _Pragma("unroll") \
    for (int j_ = 0; j_ < 2; j_++) bfr[j_] = *(const bf16x8*)&S[s][boff[j_]]; \
    _Pragma("unroll") \
    for (int i_ = 0; i_ < 4; i_++) \
        _Pragma("unroll") \
        for (int j_ = 0; j_ < 2; j_++) \
            acc[i_][j_] = __builtin_amdgcn_mfma_f32_16x16x32_bf16(af[i_], bfr[j_], acc[i_][j_], 0, 0, 0); \
} while (0)

template <int EPI>
__global__ __launch_bounds__(256, 6)
void gemm_nt(const unsigned short* __restrict__ A, const unsigned short* __restrict__ B,
             unsigned short* __restrict__ H, const float* __restrict__ fcw,
             float* __restrict__ out, float2* __restrict__ partials) {
    __shared__ unsigned short S[2][6144];   // 2 stages x (A 8KB + B 4KB)
    __shared__ float r0[4], r1[4];

    int x = blockIdx.x & 7;            // XCD id (round-robin heuristic)
    int g = blockIdx.x >> 3;           // 0..391 within XCD
    int bm = x + 8 * (g >> 3);         // bm % 8 == x; 8 bn-blocks of one bm adjacent -> A-tile
    int bn = g & 7;                    // fetched once, re-read 7x from that XCD's own L2
    if (bm >= M_TILES) {               // 8 guard blocks idle
        if (EPI == 2 && threadIdx.x == 0) partials[blockIdx.x] = make_float2(0.f, 0.f);
        return;
    }

    int t = threadIdx.x;
    int lane = t & 63;
    int wave = t >> 6;
    int m_off = (wave >> 1) * 64;      // 2x2 waves over the 128x64 tile
    int n_off = (wave & 1) * 32;
    int lrow = lane & 15;
    int lch = lane >> 4;               // 16B k-chunk index 0..3

    f32x4 acc[4][2];
#pragma unroll
    for (int i = 0; i < 4; i++)
#pragma unroll
        for (int j = 0; j < 2; j++) acc[i][j] = (f32x4){0.f, 0.f, 0.f, 0.f};

    // swizzled ds_read offsets (lane-constant, computed once): chunk' = lch ^ ((row>>1)&3)
    int aoff[4], boff[2];
#pragma unroll
    for (int i = 0; i < 4; i++) {
        int r = m_off + i * 16 + lrow;
        aoff[i] = r * 32 + ((lch ^ ((r >> 1) & 3)) * 8);
    }
#pragma unroll
    for (int j = 0; j < 2; j++) {
        int r = n_off + j * 16 + lrow;
        boff[j] = 4096 + r * 32 + ((lch ^ ((r >> 1) & 3)) * 8);
    }

    // staging: thread t -> LDS linear slot (row t>>2, chunk t&3); global source chunk is
    // pre-swizzled so LDS(row, c') holds global chunk c' ^ ((row>>1)&3).
    int trow = t >> 2;
    int tchk = ((t & 3) ^ ((t >> 3) & 3)) * 8;
    const unsigned short* ga = A + (size_t)(bm * 128 + trow) * KDIM + tchk;
    const unsigned short* gb = B + (size_t)(bn * 64 + trow) * KDIM + tchk;

    STAGE(0, 0);
    SYNC0();
#pragma unroll 1
    for (int ks = 0; ks < 32; ks += 2) {       // KDIM/32 = 32 k-steps, 2 per trip
        STAGE(1, ks + 1);                      // ks+1 <= 31 always valid
        COMPUTE(0);
        SYNC0();
        if (ks + 2 < 32) STAGE(0, ks + 2);
        COMPUTE(1);
        SYNC0();
    }

    // epilogue: C/D layout col=lane&15, row=(lane>>4)*4+reg
    int lc = lane & 15;
    int lr = (lane >> 4) << 2;

    if (EPI == 1) {
#pragma unroll
        for (int i = 0; i < 4; i++) {
            int row0 = bm * 128 + m_off + i * 16 + lr;
#pragma unroll
            for (int j = 0; j < 2; j++) {
                int col = bn * 64 + n_off + j * 16 + lc;
                f32x4 v = acc[i][j];
#pragma unroll
                for (int r = 0; r < 4; r++)
                    H[(size_t)(row0 + r) * KDIM + col] = f2bf(fmaxf(v[r], 0.f));
            }
        }
    } else {
        float s0 = 0.f, s1 = 0.f;
#pragma unroll
        for (int i = 0; i < 4; i++) {
            int row0 = bm * 128 + m_off + i * 16 + lr;
#pragma unroll
            for (int j = 0; j < 2; j++) {
                int col = bn * 64 + n_off + j * 16 + lc;
                f32x4 v = acc[i][j];
#pragma unroll
                for (int r = 0; r < 4; r++) {
                    int row = row0 + r;
                    if (row < N_NODES) {               // pad rows excluded from out + FC
                        float vv = fmaxf(v[r], 0.f);
                        size_t off = (size_t)row * DIM + col;
                        out[off] = vv;
                        s0 += vv * fcw[off];
                        s1 += vv * fcw[FLAT_TOTAL + off];
                    }
                }
            }
        }
#pragma unroll
        for (int off = 32; off > 0; off >>= 1) {
            s0 += __shfl_down(s0, off);
            s1 += __shfl_down(s1, off);
        }
        if (lane == 0) { r0[wave] = s0; r1[wave] = s1; }
        __syncthreads();
        if (t == 0)
            partials[blockIdx.x] = make_float2(r0[0] + r0[1] + r0[2] + r0[3],
                                               r1[0] + r1[1] + r1[2] + r1[3]);
    }
}

// ---------------- final reduce + log_softmax ----------------
__global__ void reduce_finalize(const float2* __restrict__ partials, const float* __restrict__ fcb,
                                float* __restrict__ out2) {
    float s0 = 0.f, s1 = 0.f;
    for (int k = threadIdx.x; k < GEMM_GRID; k += 1024) {
        float2 pr = partials[k];
        s0 += pr.x; s1 += pr.y;
    }
#pragma unroll
    for (int off = 32; off > 0; off >>= 1) {
        s0 += __shfl_down(s0, off);
        s1 += __shfl_down(s1, off);
    }
    __shared__ float r0[16], r1[16];
    int lane = threadIdx.x & 63, w = threadIdx.x >> 6;
    if (lane == 0) { r0[w] = s0; r1[w] = s1; }
    __syncthreads();
    if (threadIdx.x == 0) {
        float l0 = fcb[0], l1 = fcb[1];
#pragma unroll
        for (int k = 0; k < 16; k++) { l0 += r0[k]; l1 += r1[k]; }
        float m = fmaxf(l0, l1);
        float lse = m + logf(expf(l0 - m) + expf(l1 - m));
        out2[0] = l0 - lse;
        out2[1] = l1 - lse;
    }
}

// ---------------- launch ----------------
extern "C" void kernel_launch(void* const* d_in, const int* in_sizes, int n_in,
                              void* d_out, int out_size, void* d_ws, size_t ws_size,
                              hipStream_t stream) {
    const float* x   = (const float*)d_in[0];
    const int*   n1  = (const int*)d_in[1];
    const int*   n2  = (const int*)d_in[2];
    const float* W1  = (const float*)d_in[3];
    const float* W2  = (const float*)d_in[4];
    const float* fcw = (const float*)d_in[5];
    const float* fcb = (const float*)d_in[6];
    float* out = (float*)d_out;

    // workspace layout (16B aligned). Pad rows (50000..50047) stay 0xAA poison = tiny
    // finite bf16 values -> safe garbage through the GEMMs, masked out of the output.
    char* ws = (char*)d_ws;
    const size_t XA_OFF = 0;                                     // NPAD*1024 bf16 = 102.5 MB  [x | agg1]
    const size_t HA_OFF = XA_OFF + (size_t)NPAD * KDIM * 2;      // NPAD*1024 bf16 = 102.5 MB  [h1 | agg2]
    const size_t W1_OFF = HA_OFF + (size_t)NPAD * KDIM * 2;      // 1 MB
    const size_t W2_OFF = W1_OFF + (size_t)DIM * KDIM * 2;       // 1 MB
    const size_t P_OFF  = W2_OFF + (size_t)DIM * KDIM * 2;       // GEMM_GRID float2
    unsigned short* XA  = (unsigned short*)(ws + XA_OFF);
    unsigned short* HA  = (unsigned short*)(ws + HA_OFF);
    unsigned short* W1r = (unsigned short*)(ws + W1_OFF);
    unsigned short* W2r = (unsigned short*)(ws + W2_OFF);
    float2* partials    = (float2*)(ws + P_OFF);

    cast_w2<<<512, 256, 0, stream>>>(W1, W2, W1r, W2r);
    cast_x<<<12500, 256, 0, stream>>>(x, XA);

    agg_mean<<<NBLK_AGG, 256, 0, stream>>>(XA, n1);
    gemm_nt<1><<<GEMM_GRID, 256, 0, stream>>>(XA, W1r, HA, nullptr, nullptr, nullptr);
    agg_mean<<<NBLK_AGG, 256, 0, stream>>>(HA, n2);
    gemm_nt<2><<<GEMM_GRID, 256, 0, stream>>>(HA, W2r, nullptr, fcw, out, partials);

    reduce_finalize<<<1, 1024, 0, stream>>>(partials, fcb, out + FLAT_TOTAL);
}

// Round 4
// 589.200 us; speedup vs baseline: 1.1289x; 1.0653x over previous
//
#include <hip/hip_runtime.h>
#include <stdint.h>

// ---------------- types ----------------
typedef short bf16x8 __attribute__((ext_vector_type(8)));          // 8 bf16 in 4 VGPRs (MFMA A/B frag)
typedef float f32x4 __attribute__((ext_vector_type(4)));           // MFMA C/D frag
typedef unsigned short u16x8 __attribute__((ext_vector_type(8)));  // 16B bf16 chunk

#define N_NODES 50000
#define DIM 512                  // feature width
#define KDIM 1024                // GEMM K = [h | agg]
#define NPAD 50048               // 391 * 128
#define M_TILES 391              // 128-row tiles
#define GEMM_GRID 3136           // 8 XCDs * 392 slots (8 guard blocks idle); 391 bm x 8 bn useful
#define FLAT_TOTAL 25600000ULL   // N_NODES * DIM
#define NBLK_AGG 12500           // N_NODES / 4 rows per block

__device__ __forceinline__ unsigned short f2bf(float f) {
    unsigned u = __float_as_uint(f);
    unsigned r = u + 0x7FFFu + ((u >> 16) & 1u);   // RNE
    return (unsigned short)(r >> 16);
}
__device__ __forceinline__ float bf2f(unsigned short h) {
    return __uint_as_float(((unsigned)h) << 16);
}

// async global -> LDS, 16B per lane. LDS dest must be wave-uniform base + lane*16.
__device__ __forceinline__ void llds16(const void* g, void* l) {
    __builtin_amdgcn_global_load_lds(
        (const __attribute__((address_space(1))) void*)g,
        (__attribute__((address_space(3))) void*)l,
        16, 0, 0);
}

// ---------------- cast x: fp32 [50000,512] -> bf16 into XA[:, 0:512] (stride 1024) ----------------
__global__ void cast_x(const float* __restrict__ x, unsigned short* __restrict__ XA) {
    size_t idx = ((size_t)blockIdx.x * blockDim.x + threadIdx.x) * 8;  // 12500*256*8 = 25.6M exactly
    float4 v0 = *(const float4*)&x[idx];
    float4 v1 = *(const float4*)&x[idx + 4];
    u16x8 r;
    r[0] = f2bf(v0.x); r[1] = f2bf(v0.y); r[2] = f2bf(v0.z); r[3] = f2bf(v0.w);
    r[4] = f2bf(v1.x); r[5] = f2bf(v1.y); r[6] = f2bf(v1.z); r[7] = f2bf(v1.w);
    size_t row = idx >> 9;
    size_t col = idx & 511;
    *(u16x8*)&XA[row * KDIM + col] = r;
}

// ---------------- both W [512,1024] fp32 -> bf16, straight layout, one launch ----------------
__global__ void cast_w2(const float* __restrict__ w1, const float* __restrict__ w2,
                        unsigned short* __restrict__ o1, unsigned short* __restrict__ o2) {
    int b = blockIdx.x;
    const float* w = (b < 256) ? w1 : w2;
    unsigned short* o = (b < 256) ? o1 : o2;
    int idx = ((b & 255) * 256 + threadIdx.x) * 8;     // 524288 elems per matrix
    float4 v0 = *(const float4*)&w[idx];
    float4 v1 = *(const float4*)&w[idx + 4];
    u16x8 r;
    r[0] = f2bf(v0.x); r[1] = f2bf(v0.y); r[2] = f2bf(v0.z); r[3] = f2bf(v0.w);
    r[4] = f2bf(v1.x); r[5] = f2bf(v1.y); r[6] = f2bf(v1.z); r[7] = f2bf(v1.w);
    *(u16x8*)&o[idx] = r;
}

// ---------------- agg: buf[i, 512:1024] = 0.5*(buf[n0, 0:512] + buf[n1, 0:512]) ----------------
__global__ void agg_mean(unsigned short* __restrict__ buf, const int* __restrict__ nb) {
    int t = threadIdx.x;
    int i = blockIdx.x * 4 + (t >> 6);          // 4 rows per block, one wave each
    int lane = t & 63;
    int c = lane * 8;
    int n0 = nb[i * 2], n1 = nb[i * 2 + 1];
    u16x8 a = *(const u16x8*)&buf[(size_t)n0 * KDIM + c];
    u16x8 b = *(const u16x8*)&buf[(size_t)n1 * KDIM + c];
    u16x8 o;
#pragma unroll
    for (int j = 0; j < 8; j++)
        o[j] = f2bf(0.5f * (bf2f(a[j]) + bf2f(b[j])));
    *(u16x8*)&buf[(size_t)i * KDIM + 512 + c] = o;
}

// ---------------- GEMM: H[M,512] = relu(A[M,1024] * B[512,1024]^T) ----------------
// 128x64 tile, K-step 32, 4-deep LDS pipeline with COUNTED vmcnt (T3+T4):
// per step s: {wait vmcnt(3) lgkmcnt(0); barrier; STAGE buf[(s+2)%4] for ks=s+2; COMPUTE buf[s%4]}.
// Loads issued at step s are consumed at s+2 (2-step slack covers HBM latency); vmcnt NEVER
// drains to 0 in the loop (r3's vmcnt(0)-per-step put full load latency on the critical path
// 32x -> 4900 cyc/step, MfmaUtil 11%). Overwrite hazard: STAGE at s targets the buffer
// computed at s-2; its ds_reads were drained by step s-1's lgkmcnt(0)+barrier -> safe.
// Race lessons kept: lgkmcnt(0) before every barrier, sched_barrier(0) fences (rule #18).
// XOR-swizzled LDS (both-sides, rule #21) -> 0 bank conflicts (verified r3).
// Epilogue goes through an LDS transpose so H is written in 128B contiguous chunks
// (r3: 2B scattered stores -> WRITE_SIZE 127MB vs 51MB ideal).
// EPI==1: bf16 relu into H (stride KDIM). EPI==2: fp32 relu into out + fused FC partials.

#define SB4 6144                 // shorts per stage buffer (A 8KB + B 4KB)

#define STAGE(b, ks) do { \
    int koff_ = (ks) * 32; \
    llds16(ga + koff_,            &S[(b) * SB4 + t * 8]); \
    llds16(ga + koff_ + 64*KDIM,  &S[(b) * SB4 + 2048 + t * 8]); \
    llds16(gb + koff_,            &S[(b) * SB4 + 4096 + t * 8]); \
} while (0)

#define COMPUTE(b) do { \
    bf16x8 af[4], bfr[2]; \
    _Pragma("unroll") \
    for (int i_ = 0; i_ < 4; i_++) af[i_] = *(const bf16x8*)&S[(b) * SB4 + aoff[i_]]; \
    _Pragma("unroll") \
    for (int j_ = 0; j_ < 2; j_++) bfr[j_] = *(const bf16x8*)&S[(b) * SB4 + boff[j_]]; \
    __builtin_amdgcn_s_setprio(1); \
    _Pragma("unroll") \
    for (int i_ = 0; i_ < 4; i_++) \
        _Pragma("unroll") \
        for (int j_ = 0; j_ < 2; j_++) \
            acc[i_][j_] = __builtin_amdgcn_mfma_f32_16x16x32_bf16(af[i_], bfr[j_], acc[i_][j_], 0, 0, 0); \
    __builtin_amdgcn_s_setprio(0); \
} while (0)

#define WAITBAR(vm) do { \
    asm volatile("s_waitcnt vmcnt(" #vm ") lgkmcnt(0)" ::: "memory"); \
    __builtin_amdgcn_sched_barrier(0); \
    __builtin_amdgcn_s_barrier(); \
    __builtin_amdgcn_sched_barrier(0); \
} while (0)

#define STEP(cb, sb, ks_) do { \
    WAITBAR(3); \
    STAGE(sb, ks_); \
    COMPUTE(cb); \
} while (0)

template <int EPI>
__global__ __launch_bounds__(256, 3)
void gemm_nt(const unsigned short* __restrict__ A, const unsigned short* __restrict__ B,
             unsigned short* __restrict__ H, const float* __restrict__ fcw,
             float* __restrict__ out, float2* __restrict__ partials) {
    __shared__ unsigned short S[4 * SB4];   // 4 stages x 12KB = 48KB; reused by epilogue transpose
    __shared__ float r0[4], r1[4];

    int x = blockIdx.x & 7;            // XCD id (round-robin heuristic)
    int g = blockIdx.x >> 3;           // 0..391 within XCD
    int bm = x + 8 * (g >> 3);         // bm % 8 == x; 8 bn-blocks of one bm adjacent -> A-tile
    int bn = g & 7;                    // fetched once, re-read 7x from that XCD's own L2
    if (bm >= M_TILES) {               // 8 guard blocks idle
        if (EPI == 2 && threadIdx.x == 0) partials[blockIdx.x] = make_float2(0.f, 0.f);
        return;
    }

    int t = threadIdx.x;
    int lane = t & 63;
    int wave = t >> 6;
    int m_off = (wave >> 1) * 64;      // 2x2 waves over the 128x64 tile
    int n_off = (wave & 1) * 32;
    int lrow = lane & 15;
    int lch = lane >> 4;               // 16B k-chunk index 0..3

    f32x4 acc[4][2];
#pragma unroll
    for (int i = 0; i < 4; i++)
#pragma unroll
        for (int j = 0; j < 2; j++) acc[i][j] = (f32x4){0.f, 0.f, 0.f, 0.f};

    // swizzled ds_read offsets (lane-constant): chunk' = lch ^ ((row>>1)&3)
    int aoff[4], boff[2];
#pragma unroll
    for (int i = 0; i < 4; i++) {
        int r = m_off + i * 16 + lrow;
        aoff[i] = r * 32 + ((lch ^ ((r >> 1) & 3)) * 8);
    }
#pragma unroll
    for (int j = 0; j < 2; j++) {
        int r = n_off + j * 16 + lrow;
        boff[j] = 4096 + r * 32 + ((lch ^ ((r >> 1) & 3)) * 8);
    }

    // staging: thread t -> LDS linear slot (row t>>2, chunk t&3); global source chunk
    // pre-swizzled so LDS(row, c') holds global chunk c' ^ ((row>>1)&3).
    int trow = t >> 2;
    int tchk = ((t & 3) ^ ((t >> 3) & 3)) * 8;
    const unsigned short* ga = A + (size_t)(bm * 128 + trow) * KDIM + tchk;
    const unsigned short* gb = B + (size_t)(bn * 64 + trow) * KDIM + tchk;

    // prologue: 2 stages in flight before first wait
    STAGE(0, 0);
    STAGE(1, 1);

    // steps 0..27 (7 trips x 4); stage targets ks+2 <= 29
#pragma unroll 1
    for (int trip = 0; trip < 7; trip++) {
        int ks = trip * 4;
        STEP(0, 2, ks + 2);
        STEP(1, 3, ks + 3);
        STEP(2, 0, ks + 4);
        STEP(3, 1, ks + 5);
    }
    // steps 28..31 peeled (last stages at 28/29; drains at 30/31)
    STEP(0, 2, 30);
    STEP(1, 3, 31);
    WAITBAR(3);  COMPUTE(2);           // outstanding: ks=30,31 sets -> vm3 drains ks=30
    WAITBAR(0);  COMPUTE(3);           // drain last set

    // -------- epilogue via LDS transpose (coalesced global writes) --------
    asm volatile("s_waitcnt lgkmcnt(0)" ::: "memory");   // my ds_reads done (regs valid)
    __builtin_amdgcn_sched_barrier(0);
    __builtin_amdgcn_s_barrier();                        // all waves done reading S
    __builtin_amdgcn_sched_barrier(0);

    int lc = lane & 15;
    int lr = (lane >> 4) << 2;

    if (EPI == 1) {
        // bf16 tile [128][72] (pad 8 to break bank alignment), 18.4KB in S
        unsigned short* Ct = S;
#pragma unroll
        for (int i = 0; i < 4; i++)
#pragma unroll
            for (int j = 0; j < 2; j++) {
                f32x4 v = acc[i][j];
#pragma unroll
                for (int r = 0; r < 4; r++)
                    Ct[(m_off + i * 16 + lr + r) * 72 + n_off + j * 16 + lc] =
                        f2bf(fmaxf(v[r], 0.f));
            }
        __syncthreads();
#pragma unroll
        for (int it = 0; it < 4; it++) {
            int ci = it * 256 + t;             // 0..1023 = 128 rows x 8 chunks
            int row = ci >> 3;
            int ch = (ci & 7) * 8;
            u16x8 v = *(const u16x8*)&Ct[row * 72 + ch];
            *(u16x8*)&H[(size_t)(bm * 128 + row) * KDIM + bn * 64 + ch] = v;
        }
    } else {
        // fp32 tile [128][72] = 36.9KB in S
        float* Cf = (float*)S;
#pragma unroll
        for (int i = 0; i < 4; i++)
#pragma unroll
            for (int j = 0; j < 2; j++) {
                f32x4 v = acc[i][j];
#pragma unroll
                for (int r = 0; r < 4; r++)
                    Cf[(m_off + i * 16 + lr + r) * 72 + n_off + j * 16 + lc] =
                        fmaxf(v[r], 0.f);
            }
        __syncthreads();
        float s0 = 0.f, s1 = 0.f;
#pragma unroll
        for (int it = 0; it < 8; it++) {
            int ci = it * 256 + t;             // 0..2047 = 128 rows x 16 chunks
            int row = ci >> 4;
            int ch = (ci & 15) * 4;
            int grow = bm * 128 + row;
            if (grow < N_NODES) {              // pad rows excluded from out + FC
                float4 v = *(const float4*)&Cf[row * 72 + ch];
                size_t off = (size_t)grow * DIM + bn * 64 + ch;
                *(float4*)&out[off] = v;
                float4 a = *(const float4*)&fcw[off];
                float4 b = *(const float4*)&fcw[FLAT_TOTAL + off];
                s0 += v.x * a.x + v.y * a.y + v.z * a.z + v.w * a.w;
                s1 += v.x * b.x + v.y * b.y + v.z * b.z + v.w * b.w;
            }
        }
#pragma unroll
        for (int off = 32; off > 0; off >>= 1) {
            s0 += __shfl_down(s0, off);
            s1 += __shfl_down(s1, off);
        }
        if (lane == 0) { r0[wave] = s0; r1[wave] = s1; }
        __syncthreads();
        if (t == 0)
            partials[blockIdx.x] = make_float2(r0[0] + r0[1] + r0[2] + r0[3],
                                               r1[0] + r1[1] + r1[2] + r1[3]);
    }
}

// ---------------- final reduce + log_softmax ----------------
__global__ void reduce_finalize(const float2* __restrict__ partials, const float* __restrict__ fcb,
                                float* __restrict__ out2) {
    float s0 = 0.f, s1 = 0.f;
    for (int k = threadIdx.x; k < GEMM_GRID; k += 1024) {
        float2 pr = partials[k];
        s0 += pr.x; s1 += pr.y;
    }
#pragma unroll
    for (int off = 32; off > 0; off >>= 1) {
        s0 += __shfl_down(s0, off);
        s1 += __shfl_down(s1, off);
    }
    __shared__ float r0[16], r1[16];
    int lane = threadIdx.x & 63, w = threadIdx.x >> 6;
    if (lane == 0) { r0[w] = s0; r1[w] = s1; }
    __syncthreads();
    if (threadIdx.x == 0) {
        float l0 = fcb[0], l1 = fcb[1];
#pragma unroll
        for (int k = 0; k < 16; k++) { l0 += r0[k]; l1 += r1[k]; }
        float m = fmaxf(l0, l1);
        float lse = m + logf(expf(l0 - m) + expf(l1 - m));
        out2[0] = l0 - lse;
        out2[1] = l1 - lse;
    }
}

// ---------------- launch ----------------
extern "C" void kernel_launch(void* const* d_in, const int* in_sizes, int n_in,
                              void* d_out, int out_size, void* d_ws, size_t ws_size,
                              hipStream_t stream) {
    const float* x   = (const float*)d_in[0];
    const int*   n1  = (const int*)d_in[1];
    const int*   n2  = (const int*)d_in[2];
    const float* W1  = (const float*)d_in[3];
    const float* W2  = (const float*)d_in[4];
    const float* fcw = (const float*)d_in[5];
    const float* fcb = (const float*)d_in[6];
    float* out = (float*)d_out;

    // workspace layout (16B aligned). Pad rows (50000..50047) stay 0xAA poison = tiny
    // finite bf16 values -> safe garbage through the GEMMs, masked out of the output.
    char* ws = (char*)d_ws;
    const size_t XA_OFF = 0;                                     // NPAD*1024 bf16 = 102.5 MB  [x | agg1]
    const size_t HA_OFF = XA_OFF + (size_t)NPAD * KDIM * 2;      // NPAD*1024 bf16 = 102.5 MB  [h1 | agg2]
    const size_t W1_OFF = HA_OFF + (size_t)NPAD * KDIM * 2;      // 1 MB
    const size_t W2_OFF = W1_OFF + (size_t)DIM * KDIM * 2;       // 1 MB
    const size_t P_OFF  = W2_OFF + (size_t)DIM * KDIM * 2;       // GEMM_GRID float2
    unsigned short* XA  = (unsigned short*)(ws + XA_OFF);
    unsigned short* HA  = (unsigned short*)(ws + HA_OFF);
    unsigned short* W1r = (unsigned short*)(ws + W1_OFF);
    unsigned short* W2r = (unsigned short*)(ws + W2_OFF);
    float2* partials    = (float2*)(ws + P_OFF);

    cast_w2<<<512, 256, 0, stream>>>(W1, W2, W1r, W2r);
    cast_x<<<12500, 256, 0, stream>>>(x, XA);

    agg_mean<<<NBLK_AGG, 256, 0, stream>>>(XA, n1);
    gemm_nt<1><<<GEMM_GRID, 256, 0, stream>>>(XA, W1r, HA, nullptr, nullptr, nullptr);
    agg_mean<<<NBLK_AGG, 256, 0, stream>>>(HA, n2);
    gemm_nt<2><<<GEMM_GRID, 256, 0, stream>>>(HA, W2r, nullptr, fcw, out, partials);

    reduce_finalize<<<1, 1024, 0, stream>>>(partials, fcb, out + FLAT_TOTAL);
}

// Round 5
// 568.399 us; speedup vs baseline: 1.1702x; 1.0366x over previous
//
#include <hip/hip_runtime.h>
#include <stdint.h>

// ---------------- types ----------------
typedef short bf16x8 __attribute__((ext_vector_type(8)));          // 8 bf16 in 4 VGPRs (MFMA A/B frag)
typedef float f32x4 __attribute__((ext_vector_type(4)));           // MFMA C/D frag
typedef unsigned short u16x8 __attribute__((ext_vector_type(8)));  // 16B bf16 chunk

#define N_NODES 50000
#define DIM 512                  // feature width
#define KDIM 1024                // GEMM K = [h | agg]
#define NPAD 50048               // 391 * 128
#define M_TILES 391              // 128-row tiles
#define GEMM_GRID 1568           // 8 XCDs * 196 slots (4 guard blocks); 391 bm x 4 bn useful
#define FLAT_TOTAL 25600000ULL   // N_NODES * DIM
#define NBLK_AGG 12500           // N_NODES / 4 rows per block

__device__ __forceinline__ unsigned short f2bf(float f) {
    unsigned u = __float_as_uint(f);
    unsigned r = u + 0x7FFFu + ((u >> 16) & 1u);   // RNE
    return (unsigned short)(r >> 16);
}
__device__ __forceinline__ float bf2f(unsigned short h) {
    return __uint_as_float(((unsigned)h) << 16);
}

// async global -> LDS, 16B per lane. LDS dest must be wave-uniform base + lane*16.
__device__ __forceinline__ void llds16(const void* g, void* l) {
    __builtin_amdgcn_global_load_lds(
        (const __attribute__((address_space(1))) void*)g,
        (__attribute__((address_space(3))) void*)l,
        16, 0, 0);
}

// ---------------- cast x: fp32 [50000,512] -> bf16 into XA[:, 0:512] (stride 1024) ----------------
__global__ void cast_x(const float* __restrict__ x, unsigned short* __restrict__ XA) {
    size_t idx = ((size_t)blockIdx.x * blockDim.x + threadIdx.x) * 8;  // 12500*256*8 = 25.6M exactly
    float4 v0 = *(const float4*)&x[idx];
    float4 v1 = *(const float4*)&x[idx + 4];
    u16x8 r;
    r[0] = f2bf(v0.x); r[1] = f2bf(v0.y); r[2] = f2bf(v0.z); r[3] = f2bf(v0.w);
    r[4] = f2bf(v1.x); r[5] = f2bf(v1.y); r[6] = f2bf(v1.z); r[7] = f2bf(v1.w);
    size_t row = idx >> 9;
    size_t col = idx & 511;
    *(u16x8*)&XA[row * KDIM + col] = r;
}

// ---------------- both W [512,1024] fp32 -> bf16, straight layout, one launch ----------------
__global__ void cast_w2(const float* __restrict__ w1, const float* __restrict__ w2,
                        unsigned short* __restrict__ o1, unsigned short* __restrict__ o2) {
    int b = blockIdx.x;
    const float* w = (b < 256) ? w1 : w2;
    unsigned short* o = (b < 256) ? o1 : o2;
    int idx = ((b & 255) * 256 + threadIdx.x) * 8;     // 524288 elems per matrix
    float4 v0 = *(const float4*)&w[idx];
    float4 v1 = *(const float4*)&w[idx + 4];
    u16x8 r;
    r[0] = f2bf(v0.x); r[1] = f2bf(v0.y); r[2] = f2bf(v0.z); r[3] = f2bf(v0.w);
    r[4] = f2bf(v1.x); r[5] = f2bf(v1.y); r[6] = f2bf(v1.z); r[7] = f2bf(v1.w);
    *(u16x8*)&o[idx] = r;
}

// ---------------- agg: buf[i, 512:1024] = 0.5*(buf[n0, 0:512] + buf[n1, 0:512]) ----------------
__global__ void agg_mean(unsigned short* __restrict__ buf, const int* __restrict__ nb) {
    int t = threadIdx.x;
    int i = blockIdx.x * 4 + (t >> 6);          // 4 rows per block, one wave each
    int lane = t & 63;
    int c = lane * 8;
    int n0 = nb[i * 2], n1 = nb[i * 2 + 1];
    u16x8 a = *(const u16x8*)&buf[(size_t)n0 * KDIM + c];
    u16x8 b = *(const u16x8*)&buf[(size_t)n1 * KDIM + c];
    u16x8 o;
#pragma unroll
    for (int j = 0; j < 8; j++)
        o[j] = f2bf(0.5f * (bf2f(a[j]) + bf2f(b[j])));
    *(u16x8*)&buf[(size_t)i * KDIM + 512 + c] = o;
}

// ---------------- GEMM: H[M,512] = relu(A[M,1024] * B[512,1024]^T) ----------------
// 128x128 tile (r4's 128x64 was LDS-pipe-bound: 40 cyc MFMA per 72 cyc ds_read per wave;
// 128x128 gives 80:96 and halves LDS bytes/FLOP), BK=32, 4-deep LDS pipeline with COUNTED
// vmcnt (T3+T4): per step s {wait vmcnt(4) lgkmcnt(0); barrier; STAGE buf[(s+2)%4] for
// ks=s+2; COMPUTE buf[s%4]}. vmcnt never drains to 0 in the loop. Overwrite hazard: STAGE
// at s targets the buffer computed at s-2 whose ds_reads drained at step s-1's lgkmcnt(0)
// +barrier. Race lessons kept (r2): lgkmcnt(0) before every barrier + sched_barrier(0)
// fences (rule #18). XOR-swizzled LDS both-sides (rule #21) -> 0 K-loop bank conflicts.
// Epilogue via LDS transpose for coalesced stores; EPI2 in two 64-row passes (fp32 tile
// doesn't fit 64KB).

#define SB 8192                  // shorts per stage buffer (A 8KB + B 8KB)

#define STAGE(b, ks) do { \
    int koff_ = (ks) * 32; \
    llds16(ga + koff_,            &S[(b) * SB + t * 8]); \
    llds16(ga + koff_ + 64*KDIM,  &S[(b) * SB + 2048 + t * 8]); \
    llds16(gb + koff_,            &S[(b) * SB + 4096 + t * 8]); \
    llds16(gb + koff_ + 64*KDIM,  &S[(b) * SB + 6144 + t * 8]); \
} while (0)

#define COMPUTE(b) do { \
    bf16x8 af[4], bfr[4]; \
    _Pragma("unroll") \
    for (int i_ = 0; i_ < 4; i_++) af[i_] = *(const bf16x8*)&S[(b) * SB + aoff[i_]]; \
    _Pragma("unroll") \
    for (int j_ = 0; j_ < 4; j_++) bfr[j_] = *(const bf16x8*)&S[(b) * SB + boff[j_]]; \
    __builtin_amdgcn_s_setprio(1); \
    _Pragma("unroll") \
    for (int i_ = 0; i_ < 4; i_++) \
        _Pragma("unroll") \
        for (int j_ = 0; j_ < 4; j_++) \
            acc[i_][j_] = __builtin_amdgcn_mfma_f32_16x16x32_bf16(af[i_], bfr[j_], acc[i_][j_], 0, 0, 0); \
    __builtin_amdgcn_s_setprio(0); \
} while (0)

#define WAITBAR(vm) do { \
    asm volatile("s_waitcnt vmcnt(" #vm ") lgkmcnt(0)" ::: "memory"); \
    __builtin_amdgcn_sched_barrier(0); \
    __builtin_amdgcn_s_barrier(); \
    __builtin_amdgcn_sched_barrier(0); \
} while (0)

#define STEP(cb, sb, ks_) do { \
    WAITBAR(4); \
    STAGE(sb, ks_); \
    COMPUTE(cb); \
} while (0)

template <int EPI>
__global__ __launch_bounds__(256, 2)
void gemm_nt(const unsigned short* __restrict__ A, const unsigned short* __restrict__ B,
             unsigned short* __restrict__ H, const float* __restrict__ fcw,
             float* __restrict__ out, float2* __restrict__ partials) {
    __shared__ unsigned short S[4 * SB];    // 4 stages x 16KB = 64KB; reused by epilogue
    __shared__ float r0[4], r1[4];

    int x = blockIdx.x & 7;            // XCD id (round-robin heuristic)
    int g = blockIdx.x >> 3;           // 0..195 within XCD
    int bm = x + 8 * (g >> 2);         // bm % 8 == x; 4 bn-blocks of one bm adjacent -> A-tile
    int bn = g & 3;                    // fetched once, re-read 3x from that XCD's own L2
    if (bm >= M_TILES) {               // 4 guard blocks idle
        if (EPI == 2 && threadIdx.x == 0) partials[blockIdx.x] = make_float2(0.f, 0.f);
        return;
    }

    int t = threadIdx.x;
    int lane = t & 63;
    int wave = t >> 6;
    int m_off = (wave >> 1) * 64;      // 2x2 waves over the 128x128 tile
    int n_off = (wave & 1) * 64;
    int lrow = lane & 15;
    int lch = lane >> 4;               // 16B k-chunk index 0..3

    f32x4 acc[4][4];
#pragma unroll
    for (int i = 0; i < 4; i++)
#pragma unroll
        for (int j = 0; j < 4; j++) acc[i][j] = (f32x4){0.f, 0.f, 0.f, 0.f};

    // swizzled ds_read offsets (lane-constant): chunk' = lch ^ ((row>>1)&3)
    int aoff[4], boff[4];
#pragma unroll
    for (int i = 0; i < 4; i++) {
        int r = m_off + i * 16 + lrow;
        aoff[i] = r * 32 + ((lch ^ ((r >> 1) & 3)) * 8);
    }
#pragma unroll
    for (int j = 0; j < 4; j++) {
        int r = n_off + j * 16 + lrow;
        boff[j] = 4096 + r * 32 + ((lch ^ ((r >> 1) & 3)) * 8);
    }

    // staging: thread t -> LDS linear slot (row t>>2, chunk t&3); global source chunk
    // pre-swizzled so LDS(row, c') holds global chunk c' ^ ((row>>1)&3).
    // (row and row+64 share the same swizzle since ((r+64)>>1)&3 == ((r>>1)&3).)
    int trow = t >> 2;
    int tchk = ((t & 3) ^ ((t >> 3) & 3)) * 8;
    const unsigned short* ga = A + (size_t)(bm * 128 + trow) * KDIM + tchk;
    const unsigned short* gb = B + (size_t)(bn * 128 + trow) * KDIM + tchk;

    // prologue: 2 stages (8 loads) in flight before first wait
    STAGE(0, 0);
    STAGE(1, 1);

    // steps 0..27 (7 trips x 4); stage targets ks+2 <= 29
#pragma unroll 1
    for (int trip = 0; trip < 7; trip++) {
        int ks = trip * 4;
        STEP(0, 2, ks + 2);
        STEP(1, 3, ks + 3);
        STEP(2, 0, ks + 4);
        STEP(3, 1, ks + 5);
    }
    // steps 28..31 peeled (last stages at 30/31)
    STEP(0, 2, 30);
    STEP(1, 3, 31);
    WAITBAR(4);  COMPUTE(2);           // drains stage ks=30
    WAITBAR(0);  COMPUTE(3);           // drains stage ks=31

    // -------- epilogue via LDS transpose (coalesced global writes) --------
    asm volatile("s_waitcnt lgkmcnt(0)" ::: "memory");   // my ds_reads done (regs valid)
    __builtin_amdgcn_sched_barrier(0);
    __builtin_amdgcn_s_barrier();                        // all waves done reading S
    __builtin_amdgcn_sched_barrier(0);

    int lc = lane & 15;
    int lr = (lane >> 4) << 2;

    if (EPI == 1) {
        // bf16 tile [128][136] (pad 8), 34.8KB in S
        unsigned short* Ct = S;
#pragma unroll
        for (int i = 0; i < 4; i++)
#pragma unroll
            for (int j = 0; j < 4; j++) {
                f32x4 v = acc[i][j];
#pragma unroll
                for (int r = 0; r < 4; r++)
                    Ct[(m_off + i * 16 + lr + r) * 136 + n_off + j * 16 + lc] =
                        f2bf(fmaxf(v[r], 0.f));
            }
        __syncthreads();
#pragma unroll
        for (int it = 0; it < 8; it++) {
            int ci = it * 256 + t;             // 0..2047 = 128 rows x 16 chunks
            int row = ci >> 4;
            int ch = (ci & 15) * 8;
            u16x8 v = *(const u16x8*)&Ct[row * 136 + ch];
            *(u16x8*)&H[(size_t)(bm * 128 + row) * KDIM + bn * 128 + ch] = v;
        }
    } else {
        // fp32 tile in two 64-row passes: [64][132] = 33.8KB in S
        float* Cf = (float*)S;
        float s0 = 0.f, s1 = 0.f;
#pragma unroll
        for (int pass = 0; pass < 2; pass++) {
            if (m_off == pass * 64) {          // waves owning these rows deposit
#pragma unroll
                for (int i = 0; i < 4; i++)
#pragma unroll
                    for (int j = 0; j < 4; j++) {
                        f32x4 v = acc[i][j];
#pragma unroll
                        for (int r = 0; r < 4; r++)
                            Cf[(i * 16 + lr + r) * 132 + n_off + j * 16 + lc] =
                                fmaxf(v[r], 0.f);
                    }
            }
            __syncthreads();
#pragma unroll
            for (int it = 0; it < 8; it++) {
                int ci = it * 256 + t;         // 0..2047 = 64 rows x 32 chunks
                int row = ci >> 5;
                int ch = (ci & 31) * 4;
                int grow = bm * 128 + pass * 64 + row;
                if (grow < N_NODES) {          // pad rows excluded from out + FC
                    float4 v = *(const float4*)&Cf[row * 132 + ch];
                    size_t off = (size_t)grow * DIM + bn * 128 + ch;
                    *(float4*)&out[off] = v;
                    float4 a = *(const float4*)&fcw[off];
                    float4 b = *(const float4*)&fcw[FLAT_TOTAL + off];
                    s0 += v.x * a.x + v.y * a.y + v.z * a.z + v.w * a.w;
                    s1 += v.x * b.x + v.y * b.y + v.z * b.z + v.w * b.w;
                }
            }
            __syncthreads();                   // pass-1 deposit must not race pass-0 reads
        }
#pragma unroll
        for (int off = 32; off > 0; off >>= 1) {
            s0 += __shfl_down(s0, off);
            s1 += __shfl_down(s1, off);
        }
        if (lane == 0) { r0[wave] = s0; r1[wave] = s1; }
        __syncthreads();
        if (t == 0)
            partials[blockIdx.x] = make_float2(r0[0] + r0[1] + r0[2] + r0[3],
                                               r1[0] + r1[1] + r1[2] + r1[3]);
    }
}

// ---------------- final reduce + log_softmax ----------------
__global__ void reduce_finalize(const float2* __restrict__ partials, const float* __restrict__ fcb,
                                float* __restrict__ out2) {
    float s0 = 0.f, s1 = 0.f;
    for (int k = threadIdx.x; k < GEMM_GRID; k += 1024) {
        float2 pr = partials[k];
        s0 += pr.x; s1 += pr.y;
    }
#pragma unroll
    for (int off = 32; off > 0; off >>= 1) {
        s0 += __shfl_down(s0, off);
        s1 += __shfl_down(s1, off);
    }
    __shared__ float r0[16], r1[16];
    int lane = threadIdx.x & 63, w = threadIdx.x >> 6;
    if (lane == 0) { r0[w] = s0; r1[w] = s1; }
    __syncthreads();
    if (threadIdx.x == 0) {
        float l0 = fcb[0], l1 = fcb[1];
#pragma unroll
        for (int k = 0; k < 16; k++) { l0 += r0[k]; l1 += r1[k]; }
        float m = fmaxf(l0, l1);
        float lse = m + logf(expf(l0 - m) + expf(l1 - m));
        out2[0] = l0 - lse;
        out2[1] = l1 - lse;
    }
}

// ---------------- launch ----------------
extern "C" void kernel_launch(void* const* d_in, const int* in_sizes, int n_in,
                              void* d_out, int out_size, void* d_ws, size_t ws_size,
                              hipStream_t stream) {
    const float* x   = (const float*)d_in[0];
    const int*   n1  = (const int*)d_in[1];
    const int*   n2  = (const int*)d_in[2];
    const float* W1  = (const float*)d_in[3];
    const float* W2  = (const float*)d_in[4];
    const float* fcw = (const float*)d_in[5];
    const float* fcb = (const float*)d_in[6];
    float* out = (float*)d_out;

    // workspace layout (16B aligned). Pad rows (50000..50047) stay 0xAA poison = tiny
    // finite bf16 values -> safe garbage through the GEMMs, masked out of the output.
    char* ws = (char*)d_ws;
    const size_t XA_OFF = 0;                                     // NPAD*1024 bf16 = 102.5 MB  [x | agg1]
    const size_t HA_OFF = XA_OFF + (size_t)NPAD * KDIM * 2;      // NPAD*1024 bf16 = 102.5 MB  [h1 | agg2]
    const size_t W1_OFF = HA_OFF + (size_t)NPAD * KDIM * 2;      // 1 MB
    const size_t W2_OFF = W1_OFF + (size_t)DIM * KDIM * 2;       // 1 MB
    const size_t P_OFF  = W2_OFF + (size_t)DIM * KDIM * 2;       // GEMM_GRID float2
    unsigned short* XA  = (unsigned short*)(ws + XA_OFF);
    unsigned short* HA  = (unsigned short*)(ws + HA_OFF);
    unsigned short* W1r = (unsigned short*)(ws + W1_OFF);
    unsigned short* W2r = (unsigned short*)(ws + W2_OFF);
    float2* partials    = (float2*)(ws + P_OFF);

    cast_w2<<<512, 256, 0, stream>>>(W1, W2, W1r, W2r);
    cast_x<<<12500, 256, 0, stream>>>(x, XA);

    agg_mean<<<NBLK_AGG, 256, 0, stream>>>(XA, n1);
    gemm_nt<1><<<GEMM_GRID, 256, 0, stream>>>(XA, W1r, HA, nullptr, nullptr, nullptr);
    agg_mean<<<NBLK_AGG, 256, 0, stream>>>(HA, n2);
    gemm_nt<2><<<GEMM_GRID, 256, 0, stream>>>(HA, W2r, nullptr, fcw, out, partials);

    reduce_finalize<<<1, 1024, 0, stream>>>(partials, fcb, out + FLAT_TOTAL);
}